// Round 8
// baseline (258.968 us; speedup 1.0000x reference)
//
#include <hip/hip_runtime.h>
#include <stdint.h>

#define DD 64
#define HH 128
#define WW 128
#define NVOX (DD * HH * WW)      // 1<<20
#define NWRD (NVOX / 32)         // 32768 words per mask
#define BATCH 2
#define NCLS 4
#define NMASK 12                 // 6 pred then 6 target
#define NSLOT 24                 // 12 combined (fg+bg CC) + 12 eroded
#define NTILE 128                // (HH/8)*(DD/8) tiles of 128x8x8 voxels
#define MAXC 2048                // fg ids ascend from 0, bg ids descend from MAXC-1
#define VNODE (NTILE * MAXC)     // virtual border node id = 262144
#define NODE_STRIDE (VNODE + 64) // ints per component-parent slot
#define NTASKW 7424              // face word-crossings per problem: 3840 y + 3584 z
#define NTASKH (2 * NTASKW)      // half-word crossings = 14848

// ---------------- global lock-free union-find (on component ids) --------
__device__ __forceinline__ int uf_find(int* P, int x) {
    while (true) {
        int p = P[x];
        if (p == x) return x;
        int gp = P[p];
        if (gp != p) P[x] = gp;   // path halving (benign race; never demotes a root)
        x = gp;
    }
}
__device__ __forceinline__ int uf_find_ro(const int* P, int x) {
    int p;
    while ((p = P[x]) != x) x = p;
    return x;
}
// dual read-only find: walks two independent chains, both loads issued per
// iteration -> 2x memory-level parallelism for latency-bound count scans.
__device__ __forceinline__ int2 uf_find2_ro(const int* P, int a, int b) {
    while (true) {
        int pa = P[a];
        int pb = P[b];
        bool da = (pa == a), db = (pb == b);
        if (da && db) return make_int2(a, b);
        a = pa; b = pb;          // converged chain just re-loads its root (L1 hit)
    }
}
__device__ __forceinline__ void uf_union(int* P, int a, int b) {
    while (true) {
        a = uf_find(P, a);
        b = uf_find(P, b);
        if (a == b) return;
        int lo = a < b ? a : b;
        int hi = a < b ? b : a;
        int old = atomicCAS(&P[hi], hi, lo);
        if (old == hi) return;
        a = lo; b = old;
    }
}

// ---------------- LDS union-find on half-word run heads (swizzled) ------
#define SW(v) ((v) + ((v) >> 5))
__device__ __forceinline__ int lfind(int* lp, int x) {
    while (true) {
        int p = lp[SW(x)];
        if (p == x) return x;
        int gp = lp[SW(p)];
        if (gp != p) lp[SW(x)] = gp;
        x = gp;
    }
}
__device__ __forceinline__ void lunion(int* lp, int a, int b) {
    while (true) {
        a = lfind(lp, a);
        b = lfind(lp, b);
        if (a == b) return;
        int lo = a < b ? a : b;
        int hi = a < b ? b : a;
        int old = atomicCAS(&lp[SW(hi)], hi, lo);
        if (old == hi) return;
        a = lo; b = old;
    }
}
// resolve a head to its component's compact id (root entries hold -k-1).
__device__ __forceinline__ int lresolve(const int* lp, int h) {
    int v = lp[SW(h)];
    while (v >= 0) v = lp[SW(v)];
    return -v - 1;
}
// start bit of the 1-run of w containing set bit p
__device__ __forceinline__ int run_head(uint32_t w, int p) {
    uint32_t below = ~w & ((1u << p) - 1u);
    return below ? (32 - __clz((int)below)) : 0;
}

// ---------------- kernels ----------------

// Build 12 bitpacked masks via ballot; zero counters (incl. done counter).
__global__ void k_masks2(const float* __restrict__ pred, const int* __restrict__ tgt,
                         uint32_t* __restrict__ maskW, int* __restrict__ counts) {
    int tid = blockIdx.x * blockDim.x + threadIdx.x;   // 0 .. BATCH*NVOX-1
    if (tid < 64) counts[tid] = 0;
    int b = tid >> 20;
    int i = tid & (NVOX - 1);
    const float* p = pred + (size_t)b * NCLS * NVOX + i;
    float x0 = p[0], x1 = p[NVOX], x2 = p[2 * NVOX], x3 = p[3 * NVOX];
    float mx = fmaxf(fmaxf(x0, x1), fmaxf(x2, x3));
    float e0 = __expf(x0 - mx), e1 = __expf(x1 - mx), e2 = __expf(x2 - mx), e3 = __expf(x3 - mx);
    float S = e0 + e1 + e2 + e3;
    int t = tgt[(size_t)b * NVOX + i];
    int lane = threadIdx.x & 63;
    int wbase = i >> 5;
    float ev[3] = {e1, e2, e3};
    for (int c = 0; c < 3; ++c) {
        unsigned long long bal = __ballot(ev[c] / S > 0.5f);
        uint32_t* M = maskW + (size_t)(b * 3 + c) * NWRD;
        if (lane == 0)  M[wbase] = (uint32_t)bal;
        if (lane == 32) M[wbase] = (uint32_t)(bal >> 32);
        unsigned long long balT = __ballot(t == c + 1);
        uint32_t* MT = maskW + (size_t)(6 + b * 3 + c) * NWRD;
        if (lane == 0)  MT[wbase] = (uint32_t)balT;
        if (lane == 32) MT[wbase] = (uint32_t)(balT >> 32);
    }
}

// 6-conn binary erosion, border_value=0, bitwise.
__global__ void k_erode(const uint32_t* __restrict__ maskW, uint32_t* __restrict__ erodW) {
    int tid = blockIdx.x * blockDim.x + threadIdx.x;   // 0 .. 12*NWRD-1
    int m = tid / NWRD;
    int w = tid - m * NWRD;
    const uint32_t* M = maskW + (size_t)m * NWRD;
    int z = w >> 9, y = (w >> 2) & 127, q = w & 3;
    uint32_t a = M[w];
    uint32_t xl = (a << 1) | (q ? (M[w - 1] >> 31) : 0u);
    uint32_t xr = (a >> 1) | (q < 3 ? (M[w + 1] << 31) : 0u);
    uint32_t ym = (y > 0)   ? M[w - 4]   : 0u;
    uint32_t yp = (y < 127) ? M[w + 4]   : 0u;
    uint32_t zm = (z > 0)   ? M[w - 512] : 0u;
    uint32_t zp = (z < 63)  ? M[w + 512] : 0u;
    erodW[tid] = a & xl & xr & ym & yp & zm & zp;
}

// Tile-local CC (128x8x8 per block, 512 threads = one per 16-bit half-word).
// COMBINED slots (pr<12): fg AND bg CC of mask m in ONE pass. fg compact ids
// ascend from 0, bg ids descend from MAXC-1. bg gets VNODE pre-link +
// per-component volume histogram (wave-aggregated LDS atomics).
// Face-row C16 emit is a FIXED fully-unrolled 16-step pack (no divergent
// head x len store loop) + 2 dwordx4 stores — every comb position has an id,
// eroded unset positions hold don't-care values (bmerge reads set bits only).
// ERODED slots (pr>=12): fg-only CC of erodW with block early-out when empty.
__global__ void k_local(const uint32_t* __restrict__ maskW, const uint32_t* __restrict__ erodW,
                        uint16_t* __restrict__ C16all, int* __restrict__ Pall,
                        uint16_t* __restrict__ volAll, int* __restrict__ tcount, int m0) {
    __shared__ int lp[8448];            // swizzled; only run-head entries live
    __shared__ uint32_t aw[256];        // per-tile word cache
    __shared__ uint32_t lvol[MAXC / 2]; // packed 2 x u16 per-component voxel counts
    __shared__ int lcount;              // packed: fgCount | bgCount<<16
    int slot = blockIdx.y;
    int pr = m0 + slot;
    bool comb = pr < 12;
    int m = comb ? pr : pr - 12;
    uint16_t* C16 = C16all + (size_t)slot * NVOX;
    int* P = Pall + (size_t)slot * NODE_STRIDE;
    int tile = blockIdx.x;                         // 0..127
    int tz = tile >> 4, ty = tile & 15;
    int t2 = threadIdx.x;                          // 0..511 : half-word index
    int lane = t2 & 63;
    int wl = t2 >> 1;                              // local word 0..255
    int h  = t2 & 1;                               // half within word
    int zl = wl >> 5, yl = (wl >> 2) & 7, q = wl & 3;
    int gw = ((tz * 8 + zl) * 128 + (ty * 8 + yl)) * 4 + q;
    uint32_t afull = comb ? maskW[m * NWRD + gw] : erodW[m * NWRD + gw];
    if (h == 0) aw[wl] = afull;
    uint32_t a16 = (afull >> (16 * h)) & 0xFFFFu;
    uint32_t av = ~a16 & 0xFFFFu;
    if (t2 == 0) lcount = 0;
    if (comb && tile == 0 && t2 == 0) P[VNODE] = VNODE;

    // eroded: block-level early-out for empty tiles (the common case)
    if (!comb) {
        int any = __syncthreads_count(a16 != 0);
        if (any == 0) {
            if (t2 == 0) tcount[slot * NTILE + tile] = 0;
            return;
        }
    }

    // s1: init run-head entries (comb: heads of BOTH value runs)
    int lbase = t2 << 4;
    uint32_t heads = comb ? (((a16 ^ (a16 << 1)) | 1u) & 0xFFFFu)
                          : (a16 & ~(a16 << 1) & 0xFFFFu);
    {
        uint32_t st = heads;
        while (st) { int p = __ffs(st) - 1; st &= st - 1; lp[SW(lbase + p)] = lbase + p; }
    }
    __syncthreads();                                // lp heads + aw visible

    // s2: intra-tile unions (neighbors from LDS word cache)
    if (comb) {
        // x link at bit0 (always a head): join previous half's bit15 run if same value
        {
            int v0 = a16 & 1;
            if (h == 1) {
                uint32_t lo = afull & 0xFFFFu;
                if ((int)((lo >> 15) & 1) == v0) {
                    uint32_t pm = v0 ? lo : (~lo & 0xFFFFu);
                    lunion(lp, lbase, lbase - 16 + run_head(pm, 15));
                }
            } else if (q) {
                uint32_t hi = aw[wl - 1] >> 16;
                if ((int)((hi >> 15) & 1) == v0) {
                    uint32_t pm = v0 ? hi : (~hi & 0xFFFFu);
                    lunion(lp, lbase, lbase - 16 + run_head(pm, 15));
                }
            }
        }
        if (yl < 7) {
            uint32_t nb = (aw[wl + 4] >> (16 * h)) & 0xFFFFu;
            uint32_t nv = ~nb & 0xFFFFu;
            uint32_t ov = a16 & nb;                 // fg-fg overlaps
            uint32_t st = ov & ~(ov << 1);
            int la = -1, lb = -1;
            while (st) {
                int p = __ffs(st) - 1; st &= st - 1;
                int ha = lbase + run_head(a16, p);
                int hb = lbase + 128 + run_head(nb, p);
                if (ha != la || hb != lb) { lunion(lp, ha, hb); la = ha; lb = hb; }
            }
            ov = av & nv;                           // bg-bg overlaps
            st = ov & ~(ov << 1);
            la = -1; lb = -1;
            while (st) {
                int p = __ffs(st) - 1; st &= st - 1;
                int ha = lbase + run_head(av, p);
                int hb = lbase + 128 + run_head(nv, p);
                if (ha != la || hb != lb) { lunion(lp, ha, hb); la = ha; lb = hb; }
            }
        }
        if (zl < 7) {
            uint32_t nb = (aw[wl + 32] >> (16 * h)) & 0xFFFFu;
            uint32_t nv = ~nb & 0xFFFFu;
            uint32_t ov = a16 & nb;
            uint32_t st = ov & ~(ov << 1);
            int la = -1, lb = -1;
            while (st) {
                int p = __ffs(st) - 1; st &= st - 1;
                int ha = lbase + run_head(a16, p);
                int hb = lbase + 1024 + run_head(nb, p);
                if (ha != la || hb != lb) { lunion(lp, ha, hb); la = ha; lb = hb; }
            }
            ov = av & nv;
            st = ov & ~(ov << 1);
            la = -1; lb = -1;
            while (st) {
                int p = __ffs(st) - 1; st &= st - 1;
                int ha = lbase + run_head(av, p);
                int hb = lbase + 1024 + run_head(nv, p);
                if (ha != la || hb != lb) { lunion(lp, ha, hb); la = ha; lb = hb; }
            }
        }
    } else if (a16) {
        if (a16 & 1u) {
            if (h == 1) {
                uint32_t lo16 = afull & 0xFFFFu;
                if (lo16 >> 15) lunion(lp, lbase, lbase - 16 + run_head(lo16, 15));
            } else if (q) {
                uint32_t hi16 = aw[wl - 1] >> 16;
                if (hi16 >> 15) lunion(lp, lbase, lbase - 16 + run_head(hi16, 15));
            }
        }
        if (yl < 7) {
            uint32_t by = (aw[wl + 4] >> (16 * h)) & 0xFFFFu;
            uint32_t ov = a16 & by;
            uint32_t st = ov & ~(ov << 1);
            int la = -1, lb = -1;
            while (st) {
                int p = __ffs(st) - 1; st &= st - 1;
                int ha = lbase + run_head(a16, p);
                int hb = lbase + 128 + run_head(by, p);
                if (ha != la || hb != lb) { lunion(lp, ha, hb); la = ha; lb = hb; }
            }
        }
        if (zl < 7) {
            uint32_t bz = (aw[wl + 32] >> (16 * h)) & 0xFFFFu;
            uint32_t ov = a16 & bz;
            uint32_t st = ov & ~(ov << 1);
            int la = -1, lb = -1;
            while (st) {
                int p = __ffs(st) - 1; st &= st - 1;
                int ha = lbase + run_head(a16, p);
                int hb = lbase + 1024 + run_head(bz, p);
                if (ha != la || hb != lb) { lunion(lp, ha, hb); la = ha; lb = hb; }
            }
        }
    }
    __syncthreads();

    // zero volume histogram (comb only; before the s3 barrier)
    if (comb) { lvol[t2] = 0; lvol[t2 + 512] = 0; }

    // s3: root heads allocate compact ids — packed wave scan (fg | bg<<16)
    int tileBase = tile * MAXC;
    {
        uint32_t rootMask = 0; int nrF = 0, nrB = 0;
        uint32_t st = heads;
        while (st) {
            int p = __ffs(st) - 1; st &= st - 1;
            int hh = lbase + p;
            if (lp[SW(hh)] == hh) {
                rootMask |= 1u << p;
                if (comb && !((a16 >> p) & 1)) ++nrB; else ++nrF;
            }
        }
        int packed = nrF | (nrB << 16);
        int pre = packed;                               // inclusive wave scan
        for (int off = 1; off < 64; off <<= 1) {
            int v = __shfl_up(pre, off);
            if (lane >= off) pre += v;
        }
        int waveTot = __shfl(pre, 63);
        int base = 0;
        if (lane == 63 && waveTot) base = atomicAdd(&lcount, waveTot);
        base = __shfl(base, 63);
        int excl = pre - packed;
        int kF = (base & 0xFFFF) + (excl & 0xFFFF);
        int kB = ((unsigned)base >> 16) + ((unsigned)excl >> 16);
        st = rootMask;
        while (st) {
            int p = __ffs(st) - 1; st &= st - 1;
            int hh = lbase + p;
            int id;
            if (!comb || ((a16 >> p) & 1)) id = kF++;
            else                           id = MAXC - 1 - (kB++);
            lp[SW(hh)] = -id - 1;
            P[tileBase + id] = tileBase + id;           // sparse parent init
        }
    }
    __syncthreads();

    if (t2 == 0) tcount[slot * NTILE + tile] = lcount;

    // s4: face-row C16 emit + bg VNODE pre-link + bg volume gather.
    int myId = -1, myLen = 0; bool multi = false;
    bool faceRow = (yl == 0 || yl == 7 || zl == 0 || zl == 7);
    if (comb || (a16 && faceRow)) {
        int i0 = (gw << 5) + 16 * h;
        int gz = tz * 8 + zl, gy = ty * 8 + yl;
        bool bordRow = comb && (gz == 0 || gz == 63 || gy == 0 || gy == 127);
        bool uniHalf = (a16 == 0xFFFFu) || (comb && a16 == 0);
        if (faceRow && uniHalf) {
            int id = lresolve(lp, lbase);
            uint32_t pk = (uint32_t)id * 0x10001u;
            uint4 v4 = make_uint4(pk, pk, pk, pk);
            uint4* dst = (uint4*)(C16 + i0);
            dst[0] = v4; dst[1] = v4;
            if (comb && a16 == 0) {
                myId = id; myLen = 16;
                if (bordRow || (q == 0 && h == 0) || (q == 3 && h == 1))
                    P[tileBase + id] = VNODE;
            }
        } else if (faceRow) {
            // fixed 16-step unrolled emit (no divergent store loop); compile-
            // time indices keep wv[] in registers (explicit full unroll).
            uint32_t wv[8] = {0, 0, 0, 0, 0, 0, 0, 0};
            int id = 0;
            bool xs = (q == 0 && h == 0), xe = (q == 3 && h == 1);
            #pragma unroll
            for (int j = 0; j < 16; ++j) {
                bool bg = comb && !((a16 >> j) & 1);
                if ((heads >> j) & 1) {
                    id = lresolve(lp, lbase + j);
                    if (bg) {
                        if (myLen == 0) myId = id;
                        else if (id != myId) multi = true;
                        if (bordRow || (xs && j == 0)) P[tileBase + id] = VNODE;
                    }
                }
                if (bg) {
                    ++myLen;
                    if (xe && j == 15) P[tileBase + id] = VNODE;
                }
                wv[j >> 1] |= ((uint32_t)(uint16_t)id) << ((j & 1) * 16);
            }
            uint4* dst = (uint4*)(C16 + i0);
            dst[0] = make_uint4(wv[0], wv[1], wv[2], wv[3]);
            dst[1] = make_uint4(wv[4], wv[5], wv[6], wv[7]);
        } else {
            // comb interior: bg gather + x-end pre-links only (no stores)
            uint32_t it = heads & av;
            int htopB = (!((a16 >> 15) & 1)) ? run_head(av, 15) : -1;
            while (it) {
                int p = __ffs(it) - 1; it &= it - 1;
                int id = lresolve(lp, lbase + p);
                uint32_t run = av >> p;
                int len = __ffs(~run) - 1;           // av < 2^16 so ~run != 0
                if (myLen == 0) myId = id;
                else if (id != myId) multi = true;
                myLen += len;
                if ((q == 0 && h == 0 && p == 0) || (q == 3 && h == 1 && p == htopB))
                    P[tileBase + id] = VNODE;
            }
        }
    }

    // s5: wave-aggregated bg volume accumulation (uniform-id waves: 1 atomic)
    if (comb) {
        unsigned long long hasMask = __ballot(myLen > 0);
        if (hasMask) {
            bool anyMulti = __any(multi);
            int firstLane = __ffsll(hasMask) - 1;
            int leadId = __shfl(myId, firstLane);
            bool uni = !anyMulti && __all(myLen == 0 || myId == leadId);
            if (uni) {
                int s = myLen;
                for (int off = 32; off; off >>= 1) s += __shfl_down(s, off);
                if (lane == 0 && s)
                    atomicAdd(&lvol[leadId >> 1], (uint32_t)s << ((leadId & 1) * 16));
            } else if (myLen > 0) {
                if (!multi) {
                    atomicAdd(&lvol[myId >> 1], (uint32_t)myLen << ((myId & 1) * 16));
                } else {
                    uint32_t st = heads & av;       // rare: re-walk bg runs
                    while (st) {
                        int p = __ffs(st) - 1; st &= st - 1;
                        int id = lresolve(lp, lbase + p);
                        uint32_t run = av >> p;
                        int len = __ffs(~run) - 1;
                        atomicAdd(&lvol[id >> 1], (uint32_t)len << ((id & 1) * 16));
                    }
                }
            }
        }
    }
    __syncthreads();

    // flush per-component bg volumes (ids descend from MAXC-1)
    if (comb) {
        int lcB = lcount >> 16;
        uint16_t* volC = volAll + (size_t)slot * (NTILE * MAXC) + tileBase;
        for (int k = t2; k < lcB; k += 512) {
            int idx = MAXC - 1 - k;
            volC[idx] = (uint16_t)((lvol[idx >> 1] >> ((idx & 1) * 16)) & 0xFFFFu);
        }
    }
}

// face merges, one thread per HALF-WORD crossing, fg/bg pass split across
// blockIdx.z (homogeneous dedup streams per wave).
__global__ void k_bmerge(const uint32_t* __restrict__ maskW, const uint32_t* __restrict__ erodW,
                         const uint16_t* __restrict__ C16all, int* __restrict__ Pall,
                         int m0) {
    int slot = blockIdx.y;
    int pr = m0 + slot;
    bool comb = pr < 12;
    int m = comb ? pr : pr - 12;
    int pass = blockIdx.z;
    if (!comb && pass) return;                     // eroded: fg pass only

    int t = blockIdx.x * blockDim.x + threadIdx.x; // 0 .. NTASKH-1
    bool act = (t < NTASKH);
    int wt = t >> 1, h = t & 1;                    // word task + half

    int w = 0, dw = 4, dv = WW, tA = 0, tB = 0;
    if (act) {
        if (wt < 3840) {                // y-face: yi in 0..14, z in 0..63, q in 0..3
            int q = wt & 3, r = wt >> 2;
            int yi = r >> 6, z = r & 63;
            int y = 8 * yi + 7;
            w = (z * 128 + y) * 4 + q;
            dw = 4; dv = WW;
            tA = ((z >> 3) * 16 + yi) * MAXC;
            tB = tA + MAXC;
        } else {                        // z-face: zi in 0..6, y in 0..127, q in 0..3
            int tt = wt - 3840;
            int q = tt & 3, r = tt >> 2;
            int zi = r >> 7, y = r & 127;
            int z = 8 * zi + 7;
            w = (z * 128 + y) * 4 + q;
            dw = 512; dv = HH * WW;
            tA = (zi * 16 + (y >> 3)) * MAXC;
            tB = tA + 16 * MAXC;
        }
    }

    uint32_t st = 0;
    if (act) {
        uint32_t a, b = 0;
        if (comb) {
            a = maskW[m * NWRD + w];
            b = maskW[m * NWRD + w + dw];
        } else {
            a = erodW[m * NWRD + w];
            if ((a >> (16 * h)) & 0xFFFFu) b = erodW[m * NWRD + w + dw];
        }
        uint32_t ah = (a >> (16 * h)) & 0xFFFFu;
        uint32_t bh = (b >> (16 * h)) & 0xFFFFu;
        if (pass) { ah = ~ah & 0xFFFFu; bh = ~bh & 0xFFFFu; }
        uint32_t ov = ah & bh;
        st = ov & ~(ov << 1);
    }

    const uint16_t* C16 = C16all + (size_t)slot * NVOX;
    int* P = Pall + (size_t)slot * NODE_STRIDE;
    int i0 = (w << 5) + 16 * h;                    // voxel base of this half

    // first head pair (sentinel -1 for inactive/empty lanes)
    int ca = -1, cb = -1, p0 = -1;
    if (st) {
        p0 = __ffs(st) - 1;
        ca = tA + C16[i0 + p0];
        cb = tB + C16[i0 + p0 + dv];
    }
    // cross-lane dedup seed: previous lane's first pair (consecutive halves)
    int la = __shfl_up(ca, 1);
    int lb = __shfl_up(cb, 1);
    if ((threadIdx.x & 63) == 0) { la = -1; lb = -1; }

    while (st) {
        int p = __ffs(st) - 1; st &= st - 1;
        int xa, xb;
        if (p == p0) { xa = ca; xb = cb; }
        else { xa = tA + C16[i0 + p]; xb = tB + C16[i0 + p + dv]; }
        if (xa != la || xb != lb) { uf_union(P, xa, xb); la = xa; lb = xb; }
    }
}

// post-merge per-tile component scan (read-only P), dual-chain MLP:
//  combined: count fg roots -> b0 (counts[m]); sum bg volumes of components
//            not joined to the border component -> cavity (counts[24+m]).
//  eroded:   count roots -> b0e (counts[12+m]).
// Packed block reduction (F | V<<16). The LAST block (device-scope done
// counter at counts[63]) computes the final loss — k_loss kernel removed.
__global__ void k_flatc(const int* __restrict__ Pall, const uint16_t* __restrict__ volAll,
                        const int* __restrict__ tcount, int* __restrict__ counts,
                        float* __restrict__ out, int m0) {
    __shared__ int sAcc;
    __shared__ int sRootV;
    int slot = blockIdx.y;
    int pr = m0 + slot;
    bool comb = pr < 12;
    int m = comb ? pr : pr - 12;
    int tile = blockIdx.x;
    const int* P = Pall + (size_t)slot * NODE_STRIDE;
    int tc = tcount[slot * NTILE + tile];
    int lcF = tc & 0xFFFF, lcB = (unsigned)tc >> 16;
    if (threadIdx.x == 0) {
        sAcc = 0;
        sRootV = comb ? uf_find_ro(P, VNODE) : 0;
    }
    __syncthreads();
    int tileBase = tile * MAXC;
    int bd = blockDim.x;
    int cnt = 0;
    // fg roots, 2 independent chains per iteration
    for (int k = threadIdx.x; k < lcF; k += 2 * bd) {
        int k2 = k + bd;
        if (k2 < lcF) {
            int2 r = uf_find2_ro(P, tileBase + k, tileBase + k2);
            cnt += (r.x == tileBase + k) + (r.y == tileBase + k2);
        } else {
            if (uf_find_ro(P, tileBase + k) == tileBase + k) ++cnt;
        }
    }
    if (comb && lcB) {
        const uint16_t* volC = volAll + (size_t)slot * (NTILE * MAXC) + tileBase;
        int rootV = sRootV;
        for (int k = threadIdx.x; k < lcB; k += 2 * bd) {
            int k2 = k + bd;
            int i1 = MAXC - 1 - k;
            if (k2 < lcB) {
                int i2 = MAXC - 1 - k2;
                int2 r = uf_find2_ro(P, tileBase + i1, tileBase + i2);
                if (r.x != rootV) cnt += (int)volC[i1] << 16;
                if (r.y != rootV) cnt += (int)volC[i2] << 16;
            } else {
                if (uf_find_ro(P, tileBase + i1) != rootV) cnt += (int)volC[i1] << 16;
            }
        }
    }
    for (int off = 32; off; off >>= 1) cnt += __shfl_down(cnt, off);
    if ((threadIdx.x & 63) == 0 && cnt) atomicAdd(&sAcc, cnt);
    __syncthreads();
    if (threadIdx.x == 0) {
        if (sAcc) {
            int f = sAcc & 0xFFFF;
            int v = (unsigned)sAcc >> 16;
            if (comb) {
                if (f) atomicAdd(&counts[m], f);
                if (v) atomicAdd(&counts[24 + m], v);
            } else if (f) {
                atomicAdd(&counts[12 + m], f);
            }
        }
        __threadfence();
        int done = atomicAdd(&counts[63], 1);
        if (done == NTILE * NSLOT - 1) {          // last block: compute loss
            __threadfence();
            float acc = 0.f;
            for (int mm = 0; mm < 6; ++mm) {
                int pb0 = atomicAdd(&counts[mm], 0);
                int pbe = atomicAdd(&counts[12 + mm], 0);
                int pcv = atomicAdd(&counts[24 + mm], 0);
                int tb0 = atomicAdd(&counts[6 + mm], 0);
                int tbe = atomicAdd(&counts[18 + mm], 0);
                int tcv = atomicAdd(&counts[30 + mm], 0);
                int pb1 = max(0, pb0 - pbe), tb1 = max(0, tb0 - tbe);
                int pb2 = pcv / 100, tb2 = tcv / 100;
                acc += fabsf((float)(pb0 - tb0)) + fabsf((float)(pb1 - tb1)) +
                       fabsf((float)(pb2 - tb2));
            }
            out[0] = 0.1f * acc / 6.0f;
        }
    }
}

// ---------------- launch ----------------
extern "C" void kernel_launch(void* const* d_in, const int* in_sizes, int n_in,
                              void* d_out, int out_size, void* d_ws, size_t ws_size,
                              hipStream_t stream) {
    const float* pred = (const float*)d_in[0];
    const int* tgt = (const int*)d_in[1];
    float* out = (float*)d_out;

    uint8_t* ws = (uint8_t*)d_ws;
    uint32_t* maskW = (uint32_t*)ws;
    size_t off = (size_t)NMASK * NWRD * 4;                 // 1.5 MB
    uint32_t* erodW = (uint32_t*)(ws + off);
    off += (size_t)NMASK * NWRD * 4;                       // +1.5 MB
    int* counts = (int*)(ws + off);
    off += 256;
    int* tcount = (int*)(ws + off);
    off += (size_t)NSLOT * NTILE * 4;                      // 12 KB
    off = (off + 255) & ~(size_t)255;

    size_t avail = ws_size > off ? ws_size - off : 0;
    // per-slot: C16 (2 MB) + P (1.05 MB) + vol (0.5 MB) = ~3.55 MB
    size_t slot_bytes = (size_t)NVOX * 2 + (size_t)NODE_STRIDE * 4
                      + (size_t)NTILE * MAXC * 2;
    int PB = (int)(avail / slot_bytes);
    if (PB > NSLOT) PB = NSLOT;
    if (PB < 1) PB = 1;

    uint16_t* C16all = (uint16_t*)(ws + off);
    int* Pall = (int*)(ws + off + (size_t)PB * NVOX * 2);
    uint16_t* volAll = (uint16_t*)(ws + off + (size_t)PB * NVOX * 2
                                   + (size_t)PB * NODE_STRIDE * 4);

    k_masks2<<<dim3((BATCH * NVOX) / 256), 256, 0, stream>>>(pred, tgt, maskW, counts);
    k_erode<<<dim3((NMASK * NWRD) / 256), 256, 0, stream>>>(maskW, erodW);

    for (int m0 = 0; m0 < NSLOT; m0 += PB) {
        int mb = PB < (NSLOT - m0) ? PB : (NSLOT - m0);
        k_local <<<dim3(NTILE, mb), 512, 0, stream>>>(maskW, erodW, C16all, Pall,
                                                      volAll, tcount, m0);
        k_bmerge<<<dim3((NTASKH + 255) / 256, mb, 2), 256, 0, stream>>>(maskW, erodW,
                                                                        C16all, Pall, m0);
        k_flatc <<<dim3(NTILE, mb), 256, 0, stream>>>(Pall, volAll, tcount, counts,
                                                      out, m0);
    }
}

// Round 9
// 212.718 us; speedup vs baseline: 1.2174x; 1.2174x over previous
//
#include <hip/hip_runtime.h>
#include <stdint.h>

#define DD 64
#define HH 128
#define WW 128
#define NVOX (DD * HH * WW)      // 1<<20
#define NWRD (NVOX / 32)         // 32768 words per mask
#define BATCH 2
#define NCLS 4
#define NMASK 12                 // 6 pred then 6 target
#define NSLOT 24                 // 12 combined (fg+bg CC) + 12 eroded
#define NTILE 128                // (HH/8)*(DD/8) tiles of 128x8x8 voxels
#define MAXC 2048                // fg ids ascend from 0, bg ids descend from MAXC-1
#define VNODE (NTILE * MAXC)     // virtual border node id = 262144
#define NODE_STRIDE (VNODE + 64) // ints per component-parent slot
#define NTASKW 7424              // face word-crossings per problem: 3840 y + 3584 z
#define NTASKH (2 * NTASKW)      // half-word crossings = 14848

// ---------------- global lock-free union-find (on component ids) --------
__device__ __forceinline__ int uf_find(int* P, int x) {
    while (true) {
        int p = P[x];
        if (p == x) return x;
        int gp = P[p];
        if (gp != p) P[x] = gp;   // path halving (benign race; never demotes a root)
        x = gp;
    }
}
__device__ __forceinline__ int uf_find_ro(const int* P, int x) {
    int p;
    while ((p = P[x]) != x) x = p;
    return x;
}
// dual read-only find: walks two independent chains, both loads issued per
// iteration -> 2x memory-level parallelism for latency-bound count scans.
__device__ __forceinline__ int2 uf_find2_ro(const int* P, int a, int b) {
    while (true) {
        int pa = P[a];
        int pb = P[b];
        bool da = (pa == a), db = (pb == b);
        if (da && db) return make_int2(a, b);
        a = pa; b = pb;          // converged chain just re-loads its root (L1 hit)
    }
}
__device__ __forceinline__ void uf_union(int* P, int a, int b) {
    while (true) {
        a = uf_find(P, a);
        b = uf_find(P, b);
        if (a == b) return;
        int lo = a < b ? a : b;
        int hi = a < b ? b : a;
        int old = atomicCAS(&P[hi], hi, lo);
        if (old == hi) return;
        a = lo; b = old;
    }
}

// ---------------- LDS union-find on half-word run heads (swizzled) ------
#define SW(v) ((v) + ((v) >> 5))
__device__ __forceinline__ int lfind(int* lp, int x) {
    while (true) {
        int p = lp[SW(x)];
        if (p == x) return x;
        int gp = lp[SW(p)];
        if (gp != p) lp[SW(x)] = gp;
        x = gp;
    }
}
__device__ __forceinline__ void lunion(int* lp, int a, int b) {
    while (true) {
        a = lfind(lp, a);
        b = lfind(lp, b);
        if (a == b) return;
        int lo = a < b ? a : b;
        int hi = a < b ? b : a;
        int old = atomicCAS(&lp[SW(hi)], hi, lo);
        if (old == hi) return;
        a = lo; b = old;
    }
}
// resolve a head to its component's compact id (root entries hold -k-1).
__device__ __forceinline__ int lresolve(const int* lp, int h) {
    int v = lp[SW(h)];
    while (v >= 0) v = lp[SW(v)];
    return -v - 1;
}
// start bit of the 1-run of w containing set bit p
__device__ __forceinline__ int run_head(uint32_t w, int p) {
    uint32_t below = ~w & ((1u << p) - 1u);
    return below ? (32 - __clz((int)below)) : 0;
}

// ---------------- kernels ----------------

// Build 12 bitpacked masks via ballot; zero counters.
__global__ void k_masks2(const float* __restrict__ pred, const int* __restrict__ tgt,
                         uint32_t* __restrict__ maskW, int* __restrict__ counts) {
    int tid = blockIdx.x * blockDim.x + threadIdx.x;   // 0 .. BATCH*NVOX-1
    if (tid < 64) counts[tid] = 0;
    int b = tid >> 20;
    int i = tid & (NVOX - 1);
    const float* p = pred + (size_t)b * NCLS * NVOX + i;
    float x0 = p[0], x1 = p[NVOX], x2 = p[2 * NVOX], x3 = p[3 * NVOX];
    float mx = fmaxf(fmaxf(x0, x1), fmaxf(x2, x3));
    float e0 = __expf(x0 - mx), e1 = __expf(x1 - mx), e2 = __expf(x2 - mx), e3 = __expf(x3 - mx);
    float S = e0 + e1 + e2 + e3;
    int t = tgt[(size_t)b * NVOX + i];
    int lane = threadIdx.x & 63;
    int wbase = i >> 5;
    float ev[3] = {e1, e2, e3};
    for (int c = 0; c < 3; ++c) {
        unsigned long long bal = __ballot(ev[c] / S > 0.5f);
        uint32_t* M = maskW + (size_t)(b * 3 + c) * NWRD;
        if (lane == 0)  M[wbase] = (uint32_t)bal;
        if (lane == 32) M[wbase] = (uint32_t)(bal >> 32);
        unsigned long long balT = __ballot(t == c + 1);
        uint32_t* MT = maskW + (size_t)(6 + b * 3 + c) * NWRD;
        if (lane == 0)  MT[wbase] = (uint32_t)balT;
        if (lane == 32) MT[wbase] = (uint32_t)(balT >> 32);
    }
}

// 6-conn binary erosion, border_value=0, bitwise.
__global__ void k_erode(const uint32_t* __restrict__ maskW, uint32_t* __restrict__ erodW) {
    int tid = blockIdx.x * blockDim.x + threadIdx.x;   // 0 .. 12*NWRD-1
    int m = tid / NWRD;
    int w = tid - m * NWRD;
    const uint32_t* M = maskW + (size_t)m * NWRD;
    int z = w >> 9, y = (w >> 2) & 127, q = w & 3;
    uint32_t a = M[w];
    uint32_t xl = (a << 1) | (q ? (M[w - 1] >> 31) : 0u);
    uint32_t xr = (a >> 1) | (q < 3 ? (M[w + 1] << 31) : 0u);
    uint32_t ym = (y > 0)   ? M[w - 4]   : 0u;
    uint32_t yp = (y < 127) ? M[w + 4]   : 0u;
    uint32_t zm = (z > 0)   ? M[w - 512] : 0u;
    uint32_t zp = (z < 63)  ? M[w + 512] : 0u;
    erodW[tid] = a & xl & xr & ym & yp & zm & zp;
}

// Tile-local CC (128x8x8 per block, 512 threads = one per 16-bit half-word).
// COMBINED slots (pr<12): fg AND bg CC of mask m in ONE pass. fg compact ids
// ascend from 0, bg ids descend from MAXC-1. bg gets VNODE pre-link +
// per-component volume histogram (wave-aggregated LDS atomics).
// Face-row C16 emit is a FIXED fully-unrolled 16-step pack (no divergent
// head x len store loop) + 2 dwordx4 stores.
// ERODED slots (pr>=12): fg-only CC of erodW with block early-out when empty.
__global__ void k_local(const uint32_t* __restrict__ maskW, const uint32_t* __restrict__ erodW,
                        uint16_t* __restrict__ C16all, int* __restrict__ Pall,
                        uint16_t* __restrict__ volAll, int* __restrict__ tcount, int m0) {
    __shared__ int lp[8448];            // swizzled; only run-head entries live
    __shared__ uint32_t aw[256];        // per-tile word cache
    __shared__ uint32_t lvol[MAXC / 2]; // packed 2 x u16 per-component voxel counts
    __shared__ int lcount;              // packed: fgCount | bgCount<<16
    int slot = blockIdx.y;
    int pr = m0 + slot;
    bool comb = pr < 12;
    int m = comb ? pr : pr - 12;
    uint16_t* C16 = C16all + (size_t)slot * NVOX;
    int* P = Pall + (size_t)slot * NODE_STRIDE;
    int tile = blockIdx.x;                         // 0..127
    int tz = tile >> 4, ty = tile & 15;
    int t2 = threadIdx.x;                          // 0..511 : half-word index
    int lane = t2 & 63;
    int wl = t2 >> 1;                              // local word 0..255
    int h  = t2 & 1;                               // half within word
    int zl = wl >> 5, yl = (wl >> 2) & 7, q = wl & 3;
    int gw = ((tz * 8 + zl) * 128 + (ty * 8 + yl)) * 4 + q;
    uint32_t afull = comb ? maskW[m * NWRD + gw] : erodW[m * NWRD + gw];
    if (h == 0) aw[wl] = afull;
    uint32_t a16 = (afull >> (16 * h)) & 0xFFFFu;
    uint32_t av = ~a16 & 0xFFFFu;
    if (t2 == 0) lcount = 0;
    if (comb && tile == 0 && t2 == 0) P[VNODE] = VNODE;

    // eroded: block-level early-out for empty tiles (the common case)
    if (!comb) {
        int any = __syncthreads_count(a16 != 0);
        if (any == 0) {
            if (t2 == 0) tcount[slot * NTILE + tile] = 0;
            return;
        }
    }

    // s1: init run-head entries (comb: heads of BOTH value runs)
    int lbase = t2 << 4;
    uint32_t heads = comb ? (((a16 ^ (a16 << 1)) | 1u) & 0xFFFFu)
                          : (a16 & ~(a16 << 1) & 0xFFFFu);
    {
        uint32_t st = heads;
        while (st) { int p = __ffs(st) - 1; st &= st - 1; lp[SW(lbase + p)] = lbase + p; }
    }
    __syncthreads();                                // lp heads + aw visible

    // s2: intra-tile unions (neighbors from LDS word cache)
    if (comb) {
        // x link at bit0 (always a head): join previous half's bit15 run if same value
        {
            int v0 = a16 & 1;
            if (h == 1) {
                uint32_t lo = afull & 0xFFFFu;
                if ((int)((lo >> 15) & 1) == v0) {
                    uint32_t pm = v0 ? lo : (~lo & 0xFFFFu);
                    lunion(lp, lbase, lbase - 16 + run_head(pm, 15));
                }
            } else if (q) {
                uint32_t hi = aw[wl - 1] >> 16;
                if ((int)((hi >> 15) & 1) == v0) {
                    uint32_t pm = v0 ? hi : (~hi & 0xFFFFu);
                    lunion(lp, lbase, lbase - 16 + run_head(pm, 15));
                }
            }
        }
        if (yl < 7) {
            uint32_t nb = (aw[wl + 4] >> (16 * h)) & 0xFFFFu;
            uint32_t nv = ~nb & 0xFFFFu;
            uint32_t ov = a16 & nb;                 // fg-fg overlaps
            uint32_t st = ov & ~(ov << 1);
            int la = -1, lb = -1;
            while (st) {
                int p = __ffs(st) - 1; st &= st - 1;
                int ha = lbase + run_head(a16, p);
                int hb = lbase + 128 + run_head(nb, p);
                if (ha != la || hb != lb) { lunion(lp, ha, hb); la = ha; lb = hb; }
            }
            ov = av & nv;                           // bg-bg overlaps
            st = ov & ~(ov << 1);
            la = -1; lb = -1;
            while (st) {
                int p = __ffs(st) - 1; st &= st - 1;
                int ha = lbase + run_head(av, p);
                int hb = lbase + 128 + run_head(nv, p);
                if (ha != la || hb != lb) { lunion(lp, ha, hb); la = ha; lb = hb; }
            }
        }
        if (zl < 7) {
            uint32_t nb = (aw[wl + 32] >> (16 * h)) & 0xFFFFu;
            uint32_t nv = ~nb & 0xFFFFu;
            uint32_t ov = a16 & nb;
            uint32_t st = ov & ~(ov << 1);
            int la = -1, lb = -1;
            while (st) {
                int p = __ffs(st) - 1; st &= st - 1;
                int ha = lbase + run_head(a16, p);
                int hb = lbase + 1024 + run_head(nb, p);
                if (ha != la || hb != lb) { lunion(lp, ha, hb); la = ha; lb = hb; }
            }
            ov = av & nv;
            st = ov & ~(ov << 1);
            la = -1; lb = -1;
            while (st) {
                int p = __ffs(st) - 1; st &= st - 1;
                int ha = lbase + run_head(av, p);
                int hb = lbase + 1024 + run_head(nv, p);
                if (ha != la || hb != lb) { lunion(lp, ha, hb); la = ha; lb = hb; }
            }
        }
    } else if (a16) {
        if (a16 & 1u) {
            if (h == 1) {
                uint32_t lo16 = afull & 0xFFFFu;
                if (lo16 >> 15) lunion(lp, lbase, lbase - 16 + run_head(lo16, 15));
            } else if (q) {
                uint32_t hi16 = aw[wl - 1] >> 16;
                if (hi16 >> 15) lunion(lp, lbase, lbase - 16 + run_head(hi16, 15));
            }
        }
        if (yl < 7) {
            uint32_t by = (aw[wl + 4] >> (16 * h)) & 0xFFFFu;
            uint32_t ov = a16 & by;
            uint32_t st = ov & ~(ov << 1);
            int la = -1, lb = -1;
            while (st) {
                int p = __ffs(st) - 1; st &= st - 1;
                int ha = lbase + run_head(a16, p);
                int hb = lbase + 128 + run_head(by, p);
                if (ha != la || hb != lb) { lunion(lp, ha, hb); la = ha; lb = hb; }
            }
        }
        if (zl < 7) {
            uint32_t bz = (aw[wl + 32] >> (16 * h)) & 0xFFFFu;
            uint32_t ov = a16 & bz;
            uint32_t st = ov & ~(ov << 1);
            int la = -1, lb = -1;
            while (st) {
                int p = __ffs(st) - 1; st &= st - 1;
                int ha = lbase + run_head(a16, p);
                int hb = lbase + 1024 + run_head(bz, p);
                if (ha != la || hb != lb) { lunion(lp, ha, hb); la = ha; lb = hb; }
            }
        }
    }
    __syncthreads();

    // zero volume histogram (comb only; before the s3 barrier)
    if (comb) { lvol[t2] = 0; lvol[t2 + 512] = 0; }

    // s3: root heads allocate compact ids — packed wave scan (fg | bg<<16)
    int tileBase = tile * MAXC;
    {
        uint32_t rootMask = 0; int nrF = 0, nrB = 0;
        uint32_t st = heads;
        while (st) {
            int p = __ffs(st) - 1; st &= st - 1;
            int hh = lbase + p;
            if (lp[SW(hh)] == hh) {
                rootMask |= 1u << p;
                if (comb && !((a16 >> p) & 1)) ++nrB; else ++nrF;
            }
        }
        int packed = nrF | (nrB << 16);
        int pre = packed;                               // inclusive wave scan
        for (int off = 1; off < 64; off <<= 1) {
            int v = __shfl_up(pre, off);
            if (lane >= off) pre += v;
        }
        int waveTot = __shfl(pre, 63);
        int base = 0;
        if (lane == 63 && waveTot) base = atomicAdd(&lcount, waveTot);
        base = __shfl(base, 63);
        int excl = pre - packed;
        int kF = (base & 0xFFFF) + (excl & 0xFFFF);
        int kB = ((unsigned)base >> 16) + ((unsigned)excl >> 16);
        st = rootMask;
        while (st) {
            int p = __ffs(st) - 1; st &= st - 1;
            int hh = lbase + p;
            int id;
            if (!comb || ((a16 >> p) & 1)) id = kF++;
            else                           id = MAXC - 1 - (kB++);
            lp[SW(hh)] = -id - 1;
            P[tileBase + id] = tileBase + id;           // sparse parent init
        }
    }
    __syncthreads();

    if (t2 == 0) tcount[slot * NTILE + tile] = lcount;

    // s4: face-row C16 emit + bg VNODE pre-link + bg volume gather.
    int myId = -1, myLen = 0; bool multi = false;
    bool faceRow = (yl == 0 || yl == 7 || zl == 0 || zl == 7);
    if (comb || (a16 && faceRow)) {
        int i0 = (gw << 5) + 16 * h;
        int gz = tz * 8 + zl, gy = ty * 8 + yl;
        bool bordRow = comb && (gz == 0 || gz == 63 || gy == 0 || gy == 127);
        bool uniHalf = (a16 == 0xFFFFu) || (comb && a16 == 0);
        if (faceRow && uniHalf) {
            int id = lresolve(lp, lbase);
            uint32_t pk = (uint32_t)id * 0x10001u;
            uint4 v4 = make_uint4(pk, pk, pk, pk);
            uint4* dst = (uint4*)(C16 + i0);
            dst[0] = v4; dst[1] = v4;
            if (comb && a16 == 0) {
                myId = id; myLen = 16;
                if (bordRow || (q == 0 && h == 0) || (q == 3 && h == 1))
                    P[tileBase + id] = VNODE;
            }
        } else if (faceRow) {
            // fixed 16-step unrolled emit (no divergent store loop); compile-
            // time indices keep wv[] in registers (explicit full unroll).
            uint32_t wv[8] = {0, 0, 0, 0, 0, 0, 0, 0};
            int id = 0;
            bool xs = (q == 0 && h == 0), xe = (q == 3 && h == 1);
            #pragma unroll
            for (int j = 0; j < 16; ++j) {
                bool bg = comb && !((a16 >> j) & 1);
                if ((heads >> j) & 1) {
                    id = lresolve(lp, lbase + j);
                    if (bg) {
                        if (myLen == 0) myId = id;
                        else if (id != myId) multi = true;
                        if (bordRow || (xs && j == 0)) P[tileBase + id] = VNODE;
                    }
                }
                if (bg) {
                    ++myLen;
                    if (xe && j == 15) P[tileBase + id] = VNODE;
                }
                wv[j >> 1] |= ((uint32_t)(uint16_t)id) << ((j & 1) * 16);
            }
            uint4* dst = (uint4*)(C16 + i0);
            dst[0] = make_uint4(wv[0], wv[1], wv[2], wv[3]);
            dst[1] = make_uint4(wv[4], wv[5], wv[6], wv[7]);
        } else {
            // comb interior: bg gather + x-end pre-links only (no stores)
            uint32_t it = heads & av;
            int htopB = (!((a16 >> 15) & 1)) ? run_head(av, 15) : -1;
            while (it) {
                int p = __ffs(it) - 1; it &= it - 1;
                int id = lresolve(lp, lbase + p);
                uint32_t run = av >> p;
                int len = __ffs(~run) - 1;           // av < 2^16 so ~run != 0
                if (myLen == 0) myId = id;
                else if (id != myId) multi = true;
                myLen += len;
                if ((q == 0 && h == 0 && p == 0) || (q == 3 && h == 1 && p == htopB))
                    P[tileBase + id] = VNODE;
            }
        }
    }

    // s5: wave-aggregated bg volume accumulation (uniform-id waves: 1 atomic)
    if (comb) {
        unsigned long long hasMask = __ballot(myLen > 0);
        if (hasMask) {
            bool anyMulti = __any(multi);
            int firstLane = __ffsll(hasMask) - 1;
            int leadId = __shfl(myId, firstLane);
            bool uni = !anyMulti && __all(myLen == 0 || myId == leadId);
            if (uni) {
                int s = myLen;
                for (int off = 32; off; off >>= 1) s += __shfl_down(s, off);
                if (lane == 0 && s)
                    atomicAdd(&lvol[leadId >> 1], (uint32_t)s << ((leadId & 1) * 16));
            } else if (myLen > 0) {
                if (!multi) {
                    atomicAdd(&lvol[myId >> 1], (uint32_t)myLen << ((myId & 1) * 16));
                } else {
                    uint32_t st = heads & av;       // rare: re-walk bg runs
                    while (st) {
                        int p = __ffs(st) - 1; st &= st - 1;
                        int id = lresolve(lp, lbase + p);
                        uint32_t run = av >> p;
                        int len = __ffs(~run) - 1;
                        atomicAdd(&lvol[id >> 1], (uint32_t)len << ((id & 1) * 16));
                    }
                }
            }
        }
    }
    __syncthreads();

    // flush per-component bg volumes (ids descend from MAXC-1)
    if (comb) {
        int lcB = lcount >> 16;
        uint16_t* volC = volAll + (size_t)slot * (NTILE * MAXC) + tileBase;
        for (int k = t2; k < lcB; k += 512) {
            int idx = MAXC - 1 - k;
            volC[idx] = (uint16_t)((lvol[idx >> 1] >> ((idx & 1) * 16)) & 0xFFFFu);
        }
    }
}

// face merges, one thread per HALF-WORD crossing, fg/bg pass split across
// blockIdx.z (homogeneous dedup streams per wave).
__global__ void k_bmerge(const uint32_t* __restrict__ maskW, const uint32_t* __restrict__ erodW,
                         const uint16_t* __restrict__ C16all, int* __restrict__ Pall,
                         int m0) {
    int slot = blockIdx.y;
    int pr = m0 + slot;
    bool comb = pr < 12;
    int m = comb ? pr : pr - 12;
    int pass = blockIdx.z;
    if (!comb && pass) return;                     // eroded: fg pass only

    int t = blockIdx.x * blockDim.x + threadIdx.x; // 0 .. NTASKH-1
    bool act = (t < NTASKH);
    int wt = t >> 1, h = t & 1;                    // word task + half

    int w = 0, dw = 4, dv = WW, tA = 0, tB = 0;
    if (act) {
        if (wt < 3840) {                // y-face: yi in 0..14, z in 0..63, q in 0..3
            int q = wt & 3, r = wt >> 2;
            int yi = r >> 6, z = r & 63;
            int y = 8 * yi + 7;
            w = (z * 128 + y) * 4 + q;
            dw = 4; dv = WW;
            tA = ((z >> 3) * 16 + yi) * MAXC;
            tB = tA + MAXC;
        } else {                        // z-face: zi in 0..6, y in 0..127, q in 0..3
            int tt = wt - 3840;
            int q = tt & 3, r = tt >> 2;
            int zi = r >> 7, y = r & 127;
            int z = 8 * zi + 7;
            w = (z * 128 + y) * 4 + q;
            dw = 512; dv = HH * WW;
            tA = (zi * 16 + (y >> 3)) * MAXC;
            tB = tA + 16 * MAXC;
        }
    }

    uint32_t st = 0;
    if (act) {
        uint32_t a, b = 0;
        if (comb) {
            a = maskW[m * NWRD + w];
            b = maskW[m * NWRD + w + dw];
        } else {
            a = erodW[m * NWRD + w];
            if ((a >> (16 * h)) & 0xFFFFu) b = erodW[m * NWRD + w + dw];
        }
        uint32_t ah = (a >> (16 * h)) & 0xFFFFu;
        uint32_t bh = (b >> (16 * h)) & 0xFFFFu;
        if (pass) { ah = ~ah & 0xFFFFu; bh = ~bh & 0xFFFFu; }
        uint32_t ov = ah & bh;
        st = ov & ~(ov << 1);
    }

    const uint16_t* C16 = C16all + (size_t)slot * NVOX;
    int* P = Pall + (size_t)slot * NODE_STRIDE;
    int i0 = (w << 5) + 16 * h;                    // voxel base of this half

    // first head pair (sentinel -1 for inactive/empty lanes)
    int ca = -1, cb = -1, p0 = -1;
    if (st) {
        p0 = __ffs(st) - 1;
        ca = tA + C16[i0 + p0];
        cb = tB + C16[i0 + p0 + dv];
    }
    // cross-lane dedup seed: previous lane's first pair (consecutive halves)
    int la = __shfl_up(ca, 1);
    int lb = __shfl_up(cb, 1);
    if ((threadIdx.x & 63) == 0) { la = -1; lb = -1; }

    while (st) {
        int p = __ffs(st) - 1; st &= st - 1;
        int xa, xb;
        if (p == p0) { xa = ca; xb = cb; }
        else { xa = tA + C16[i0 + p]; xb = tB + C16[i0 + p + dv]; }
        if (xa != la || xb != lb) { uf_union(P, xa, xb); la = xa; lb = xb; }
    }
}

// post-merge per-tile component scan (read-only P), dual-chain MLP:
//  combined: count fg roots -> b0 (counts[m]); sum bg volumes of components
//            not joined to the border component -> cavity (counts[24+m]).
//  eroded:   count roots -> b0e (counts[12+m]).
// Packed block reduction (F | V<<16; V<=8192, F<=2048 -> no overflow).
// NOTE: no device-scope fence here — the k_loss kernel-launch boundary
// provides cross-XCD visibility for free (round-8 lesson: per-block
// __threadfence() = L2 writeback on gfx950, ~40 us across 3072 blocks).
__global__ void k_flatc(const int* __restrict__ Pall, const uint16_t* __restrict__ volAll,
                        const int* __restrict__ tcount, int* __restrict__ counts, int m0) {
    __shared__ int sAcc;
    __shared__ int sRootV;
    int slot = blockIdx.y;
    int pr = m0 + slot;
    bool comb = pr < 12;
    int m = comb ? pr : pr - 12;
    int tile = blockIdx.x;
    const int* P = Pall + (size_t)slot * NODE_STRIDE;
    int tc = tcount[slot * NTILE + tile];
    int lcF = tc & 0xFFFF, lcB = (unsigned)tc >> 16;
    if (threadIdx.x == 0) {
        sAcc = 0;
        sRootV = comb ? uf_find_ro(P, VNODE) : 0;
    }
    __syncthreads();
    int tileBase = tile * MAXC;
    int bd = blockDim.x;
    int cnt = 0;
    // fg roots, 2 independent chains per iteration
    for (int k = threadIdx.x; k < lcF; k += 2 * bd) {
        int k2 = k + bd;
        if (k2 < lcF) {
            int2 r = uf_find2_ro(P, tileBase + k, tileBase + k2);
            cnt += (r.x == tileBase + k) + (r.y == tileBase + k2);
        } else {
            if (uf_find_ro(P, tileBase + k) == tileBase + k) ++cnt;
        }
    }
    if (comb && lcB) {
        const uint16_t* volC = volAll + (size_t)slot * (NTILE * MAXC) + tileBase;
        int rootV = sRootV;
        for (int k = threadIdx.x; k < lcB; k += 2 * bd) {
            int k2 = k + bd;
            int i1 = MAXC - 1 - k;
            if (k2 < lcB) {
                int i2 = MAXC - 1 - k2;
                int2 r = uf_find2_ro(P, tileBase + i1, tileBase + i2);
                if (r.x != rootV) cnt += (int)volC[i1] << 16;
                if (r.y != rootV) cnt += (int)volC[i2] << 16;
            } else {
                if (uf_find_ro(P, tileBase + i1) != rootV) cnt += (int)volC[i1] << 16;
            }
        }
    }
    for (int off = 32; off; off >>= 1) cnt += __shfl_down(cnt, off);
    if ((threadIdx.x & 63) == 0 && cnt) atomicAdd(&sAcc, cnt);
    __syncthreads();
    if (threadIdx.x == 0 && sAcc) {
        int f = sAcc & 0xFFFF;
        int v = (unsigned)sAcc >> 16;
        if (comb) {
            if (f) atomicAdd(&counts[m], f);
            if (v) atomicAdd(&counts[24 + m], v);
        } else if (f) {
            atomicAdd(&counts[12 + m], f);
        }
    }
}

__global__ void k_loss(const int* __restrict__ counts, float* __restrict__ out) {
    if (threadIdx.x != 0 || blockIdx.x != 0) return;
    float acc = 0.f;
    for (int m = 0; m < 6; ++m) {
        int pb0 = counts[m],      pbe = counts[12 + m],      pcv = counts[24 + m];
        int tb0 = counts[6 + m],  tbe = counts[12 + 6 + m],  tcv = counts[24 + 6 + m];
        int pb1 = max(0, pb0 - pbe), tb1 = max(0, tb0 - tbe);
        int pb2 = pcv / 100, tb2 = tcv / 100;
        acc += fabsf((float)(pb0 - tb0)) + fabsf((float)(pb1 - tb1)) + fabsf((float)(pb2 - tb2));
    }
    out[0] = 0.1f * acc / 6.0f;
}

// ---------------- launch ----------------
extern "C" void kernel_launch(void* const* d_in, const int* in_sizes, int n_in,
                              void* d_out, int out_size, void* d_ws, size_t ws_size,
                              hipStream_t stream) {
    const float* pred = (const float*)d_in[0];
    const int* tgt = (const int*)d_in[1];
    float* out = (float*)d_out;

    uint8_t* ws = (uint8_t*)d_ws;
    uint32_t* maskW = (uint32_t*)ws;
    size_t off = (size_t)NMASK * NWRD * 4;                 // 1.5 MB
    uint32_t* erodW = (uint32_t*)(ws + off);
    off += (size_t)NMASK * NWRD * 4;                       // +1.5 MB
    int* counts = (int*)(ws + off);
    off += 256;
    int* tcount = (int*)(ws + off);
    off += (size_t)NSLOT * NTILE * 4;                      // 12 KB
    off = (off + 255) & ~(size_t)255;

    size_t avail = ws_size > off ? ws_size - off : 0;
    // per-slot: C16 (2 MB) + P (1.05 MB) + vol (0.5 MB) = ~3.55 MB
    size_t slot_bytes = (size_t)NVOX * 2 + (size_t)NODE_STRIDE * 4
                      + (size_t)NTILE * MAXC * 2;
    int PB = (int)(avail / slot_bytes);
    if (PB > NSLOT) PB = NSLOT;
    if (PB < 1) PB = 1;

    uint16_t* C16all = (uint16_t*)(ws + off);
    int* Pall = (int*)(ws + off + (size_t)PB * NVOX * 2);
    uint16_t* volAll = (uint16_t*)(ws + off + (size_t)PB * NVOX * 2
                                   + (size_t)PB * NODE_STRIDE * 4);

    k_masks2<<<dim3((BATCH * NVOX) / 256), 256, 0, stream>>>(pred, tgt, maskW, counts);
    k_erode<<<dim3((NMASK * NWRD) / 256), 256, 0, stream>>>(maskW, erodW);

    for (int m0 = 0; m0 < NSLOT; m0 += PB) {
        int mb = PB < (NSLOT - m0) ? PB : (NSLOT - m0);
        k_local <<<dim3(NTILE, mb), 512, 0, stream>>>(maskW, erodW, C16all, Pall,
                                                      volAll, tcount, m0);
        k_bmerge<<<dim3((NTASKH + 255) / 256, mb, 2), 256, 0, stream>>>(maskW, erodW,
                                                                        C16all, Pall, m0);
        k_flatc <<<dim3(NTILE, mb), 256, 0, stream>>>(Pall, volAll, tcount, counts, m0);
    }

    k_loss<<<1, 64, 0, stream>>>(counts, out);
}